// Round 5
// baseline (233.888 us; speedup 1.0000x reference)
//
#include <hip/hip_runtime.h>

namespace {
constexpr int kB = 64;
constexpr int kM = 4096;
constexpr int kN = 8192;
constexpr int kBM = kB * kM;   // 262144
constexpr int kBN = kB * kN;   // 524288
constexpr int kG  = 4;         // chunks (blocks) per instance
constexpr int kRBlocks = 1024; // reduce grid size (must match finalize)
constexpr float W_PRIMAL = 0.1f;
constexpr float W_DUAL   = 0.1f;
constexpr float W_STAT   = 0.6f;
constexpr float W_COMP   = 0.2f;
}

// True hardware LDS fp32 atomic add (fire-and-forget). HIP's atomicAdd /
// unsafeAtomicAdd on __shared__ float expand to a ~224-cyc/instr lane-
// serialized loop (measured r2-r4: 1250 atomic instrs/CU == 278K cyc/CU);
// ds_add_f32 is the native pipelined DS op.
typedef __attribute__((address_space(3))) float lds_float;
__device__ __forceinline__ void lds_add(float* p, float v)
{
    asm volatile("ds_add_f32 %0, %1" :: "v"((lds_float*)p), "v"(v) : "memory");
}

// -------- scatter, fully LDS-resident, native ds_add_f32, 2x replicated acc --------
// Block (k,g): stage x/lam slices in LDS, accumulate 40K-nnz chunk into one of
// two replica accumulators (by wave half; halves same-bank RMW contention),
// merge replicas into coalesced partial stores. LDS = 144 KB -> 1 block/CU.
__global__ __launch_bounds__(1024, 4) void kkt_scatter(
    const float* __restrict__ a_vals,
    const int*   __restrict__ a_rows,
    const int*   __restrict__ a_cols,
    const float* __restrict__ x_hat,
    const float* __restrict__ lam_hat,
    float* __restrict__ P_ax,     // [kG][kBM]
    float* __restrict__ P_at,     // [kG][kBN]
    int nnz_per)
{
    __shared__ float s_x  [kN];      // 32 KB  instance x slice
    __shared__ float s_lam[kM];      // 16 KB  instance lam slice
    __shared__ float s_ax [2][kM];   // 32 KB  accumulator replicas
    __shared__ float s_at [2][kN];   // 64 KB  accumulator replicas

    const int tid = threadIdx.x;
    const int bs  = blockDim.x;
    const int k   = blockIdx.x / kG;
    const int g   = blockIdx.x % kG;
    const int row_base = k * kM;
    const int col_base = k * kN;

    // cooperative load of x/lam slices (coalesced float4) + zero accumulators
    {
        const float4* xg = reinterpret_cast<const float4*>(x_hat + col_base);
        const float4* lg = reinterpret_cast<const float4*>(lam_hat + row_base);
        float4* xs = reinterpret_cast<float4*>(s_x);
        float4* ls = reinterpret_cast<float4*>(s_lam);
        for (int j = tid; j < kN / 4; j += bs) xs[j] = xg[j];
        for (int j = tid; j < kM / 4; j += bs) ls[j] = lg[j];
        float4 z = {0.f, 0.f, 0.f, 0.f};
        float4* as = reinterpret_cast<float4*>(&s_ax[0][0]);
        float4* ts = reinterpret_cast<float4*>(&s_at[0][0]);
        for (int j = tid; j < 2 * kM / 4; j += bs) as[j] = z;
        for (int j = tid; j < 2 * kN / 4; j += bs) ts[j] = z;
    }
    __syncthreads();

    const int rep = tid >> 9;              // waves 0-7 -> replica 0, 8-15 -> 1
    float* ax = s_ax[rep];
    float* at = s_at[rep];

    const int chunk = nnz_per / kG;        // 40000
    const int base  = k * nnz_per + g * chunk;
    const int nq    = chunk >> 2;
    const int qbase = base >> 2;           // base % 4 == 0 for this shape

    const float4* v4 = reinterpret_cast<const float4*>(a_vals);
    const int4*   r4 = reinterpret_cast<const int4*>(a_rows);
    const int4*   c4 = reinterpret_cast<const int4*>(a_cols);

    for (int q = tid; q < nq; q += bs) {
        float4 v = v4[qbase + q];
        int4   r = r4[qbase + q];
        int4   c = c4[qbase + q];
        int rl0 = r.x - row_base, rl1 = r.y - row_base,
            rl2 = r.z - row_base, rl3 = r.w - row_base;
        int cl0 = c.x - col_base, cl1 = c.y - col_base,
            cl2 = c.z - col_base, cl3 = c.w - col_base;
        float x0 = s_x[cl0], x1 = s_x[cl1], x2 = s_x[cl2], x3 = s_x[cl3];
        float l0 = s_lam[rl0], l1 = s_lam[rl1], l2 = s_lam[rl2], l3 = s_lam[rl3];
        lds_add(&ax[rl0], v.x * x0);
        lds_add(&ax[rl1], v.y * x1);
        lds_add(&ax[rl2], v.z * x2);
        lds_add(&ax[rl3], v.w * x3);
        lds_add(&at[cl0], v.x * l0);
        lds_add(&at[cl1], v.y * l1);
        lds_add(&at[cl2], v.z * l2);
        lds_add(&at[cl3], v.w * l3);
    }
    // scalar tail (never runs when chunk % 4 == 0)
    if ((chunk & 3) && g == kG - 1 && tid == 0) {
        for (int i = base + (nq << 2); i < base + chunk; ++i) {
            float v = a_vals[i];
            lds_add(&ax[a_rows[i] - row_base], v * s_x[a_cols[i] - col_base]);
            lds_add(&at[a_cols[i] - col_base], v * s_lam[a_rows[i] - row_base]);
        }
    }
    // drain our fire-and-forget DS ops, then barrier
    asm volatile("s_waitcnt lgkmcnt(0)" ::: "memory");
    __syncthreads();

    // merge replicas + plain coalesced partial stores (no global atomics)
    {
        float4* pa = reinterpret_cast<float4*>(P_ax + (size_t)g * kBM + row_base);
        float4* pt = reinterpret_cast<float4*>(P_at + (size_t)g * kBN + col_base);
        const float4* a0 = reinterpret_cast<const float4*>(&s_ax[0][0]);
        const float4* a1 = reinterpret_cast<const float4*>(&s_ax[1][0]);
        const float4* t0 = reinterpret_cast<const float4*>(&s_at[0][0]);
        const float4* t1 = reinterpret_cast<const float4*>(&s_at[1][0]);
        for (int j = tid; j < kM / 4; j += bs) {
            float4 u = a0[j], w = a1[j];
            float4 o = {u.x + w.x, u.y + w.y, u.z + w.z, u.w + w.w};
            pa[j] = o;
        }
        for (int j = tid; j < kN / 4; j += bs) {
            float4 u = t0[j], w = t1[j];
            float4 o = {u.x + w.x, u.y + w.y, u.z + w.z, u.w + w.w};
            pt[j] = o;
        }
    }
}

// -------- fused reduction: per-block partial via plain store --------
__device__ __forceinline__ float block_reduce_sum(float v)
{
    __shared__ float smem[16];
    int lane = threadIdx.x & 63;
    int wave = threadIdx.x >> 6;
    #pragma unroll
    for (int off = 32; off > 0; off >>= 1)
        v += __shfl_down(v, off, 64);
    if (lane == 0) smem[wave] = v;
    __syncthreads();
    float s = 0.f;
    if (threadIdx.x == 0) {
        int nw = blockDim.x >> 6;
        for (int w = 0; w < nw; ++w) s += smem[w];
    }
    return s;  // valid only on thread 0
}

__global__ void kkt_reduce(const float* __restrict__ P_ax,
                           const float* __restrict__ P_at,
                           const float* __restrict__ b_pad,
                           const float* __restrict__ lam_hat,
                           const float* __restrict__ c_pad,
                           const float* __restrict__ x_hat,
                           float* __restrict__ partials)
{
    const int mq = kBM / 4;
    const int nq = kBN / 4;
    float s1 = 0.f;                  // weight 1/((M+N)*B)
    float s2 = 0.f;                  // weight W_STAT/(N*B)
    const int stride = gridDim.x * blockDim.x;
    for (int idx = blockIdx.x * blockDim.x + threadIdx.x; idx < mq + nq; idx += stride) {
        if (idx < mq) {
            float4 ax = reinterpret_cast<const float4*>(P_ax)[idx];
            #pragma unroll
            for (int g = 1; g < kG; ++g) {
                float4 p = reinterpret_cast<const float4*>(P_ax + (size_t)g * kBM)[idx];
                ax.x += p.x; ax.y += p.y; ax.z += p.z; ax.w += p.w;
            }
            float4 bb = reinterpret_cast<const float4*>(b_pad)[idx];
            float4 ll = reinterpret_cast<const float4*>(lam_hat)[idx];
            #pragma unroll
            for (int e = 0; e < 4; ++e) {
                float axmb = (&ax.x)[e] - (&bb.x)[e];
                float l    = (&ll.x)[e];
                float rp   = fmaxf(axmb, 0.f);
                float rl   = fmaxf(-l, 0.f);
                float cm   = l * axmb;
                s1 += W_PRIMAL * rp * rp + W_DUAL * rl * rl + W_COMP * cm * cm;
            }
        } else {
            int j = idx - mq;
            float4 at = reinterpret_cast<const float4*>(P_at)[j];
            #pragma unroll
            for (int g = 1; g < kG; ++g) {
                float4 p = reinterpret_cast<const float4*>(P_at + (size_t)g * kBN)[j];
                at.x += p.x; at.y += p.y; at.z += p.z; at.w += p.w;
            }
            float4 cc = reinterpret_cast<const float4*>(c_pad)[j];
            float4 xx = reinterpret_cast<const float4*>(x_hat)[j];
            #pragma unroll
            for (int e = 0; e < 4; ++e) {
                float t  = (&at.x)[e] + (&cc.x)[e];
                float mu = fmaxf(t, 0.f);
                float st = t - mu;                 // min(t,0); dual relu(-mu)^2 == 0
                float x  = (&xx.x)[e];
                float rx = fmaxf(-x, 0.f);
                float cm = mu * x;
                s1 += W_PRIMAL * rx * rx + W_COMP * cm * cm;
                s2 += st * st;
            }
        }
    }
    const float scale1 = 1.0f / ((float)(kM + kN) * (float)kB);
    const float scale2 = W_STAT / ((float)kN * (float)kB);
    float t = block_reduce_sum(s1 * scale1 + s2 * scale2);
    if (threadIdx.x == 0) partials[blockIdx.x] = t;
}

// single block sums the kRBlocks partials
__global__ __launch_bounds__(1024) void kkt_finalize(const float* __restrict__ partials,
                                                     float* __restrict__ out)
{
    float v = partials[threadIdx.x];           // blockDim.x == kRBlocks
    float t = block_reduce_sum(v);
    if (threadIdx.x == 0) out[0] = t;
}

extern "C" void kernel_launch(void* const* d_in, const int* in_sizes, int n_in,
                              void* d_out, int out_size, void* d_ws, size_t ws_size,
                              hipStream_t stream)
{
    const float* x_hat   = (const float*)d_in[0];
    const float* lam_hat = (const float*)d_in[1];
    const float* a_vals  = (const float*)d_in[2];
    const int*   a_rows  = (const int*)d_in[3];
    const int*   a_cols  = (const int*)d_in[4];
    const float* b_pad   = (const float*)d_in[5];
    const float* c_pad   = (const float*)d_in[6];
    float* out = (float*)d_out;

    const int nnz     = in_sizes[2];
    const int nnz_per = nnz / kB;

    float* P_ax     = (float*)d_ws;                     // kG*kBM floats (4 MB)
    float* P_at     = P_ax + (size_t)kG * kBM;          // kG*kBN floats (8 MB)
    float* partials = P_at + (size_t)kG * kBN;          // kRBlocks floats

    kkt_scatter<<<dim3(kB * kG), dim3(1024), 0, stream>>>(
        a_vals, a_rows, a_cols, x_hat, lam_hat, P_ax, P_at, nnz_per);

    kkt_reduce<<<dim3(kRBlocks), dim3(256), 0, stream>>>(
        P_ax, P_at, b_pad, lam_hat, c_pad, x_hat, partials);

    kkt_finalize<<<1, dim3(kRBlocks), 0, stream>>>(partials, out);
}